// Round 5
// baseline (155.711 us; speedup 1.0000x reference)
//
#include <hip/hip_runtime.h>

#define S_DIM 128
#define N_DIM 256
#define CIN   256
#define CH    32
#define COUT  128

typedef __attribute__((ext_vector_type(8))) short bf16x8;
typedef __attribute__((ext_vector_type(4))) float f32x4;

__device__ __forceinline__ unsigned short f2bf(float f) {
  union { float f; unsigned int u; } v; v.f = f;
  unsigned int u = v.u;
  return (unsigned short)((u + 0x7FFFu + ((u >> 16) & 1u)) >> 16);
}

// ---------------------------------------------------------------------------
// K0: merged streaming LN + prep. Zero LDS -> max occupancy.
//   blocks 0..2047   : LayerNorm (wave = 4 rows, fully linear read m /
//                      write mn_g bf16; mask folded in)
//   blocks 2048..2111: wab_bf = bf16(Wa|Wb), row-major 64 x 256
//   blocks 2112..2239: wo2 = Wo bf16 permuted to [ot][kk][lane][8] (GEMM2
//                      B-frag = one coalesced 16B/lane read), k' = d*32+c
//   blocks 2240..2495: rnm = 1 / clip(mask^T mask, 1)
// ---------------------------------------------------------------------------
__global__ __launch_bounds__(256) void k0_ln_prep(
    const float* __restrict__ m, const float* __restrict__ mask,
    const float* __restrict__ gamma, const float* __restrict__ beta,
    const float* __restrict__ Wa, const float* __restrict__ Wb,
    const float* __restrict__ Wo,
    float* __restrict__ rnm, unsigned short* __restrict__ wab_bf,
    unsigned short* __restrict__ wo2, unsigned short* __restrict__ mn_g) {
  const int b = blockIdx.x, t = threadIdx.x;
  if (b < 2048) {
    const int w = t >> 6, l = t & 63;
    const int rbase = b * 16 + w * 4;          // rows rid = s*256 + i
    const float4 g4 = *(const float4*)(gamma + l * 4);
    const float4 b4 = *(const float4*)(beta + l * 4);
    float4 v[4];
    #pragma unroll
    for (int rr = 0; rr < 4; rr++)
      v[rr] = *(const float4*)(m + (size_t)(rbase + rr) * CIN + l * 4);
    #pragma unroll
    for (int rr = 0; rr < 4; rr++) {
      float sum = v[rr].x + v[rr].y + v[rr].z + v[rr].w;
      float sq  = v[rr].x * v[rr].x + v[rr].y * v[rr].y +
                  v[rr].z * v[rr].z + v[rr].w * v[rr].w;
      #pragma unroll
      for (int off = 32; off > 0; off >>= 1) {
        sum += __shfl_down(sum, off);
        sq  += __shfl_down(sq, off);
      }
      sum = __shfl(sum, 0); sq = __shfl(sq, 0);
      const float mu = sum * (1.0f / CIN);
      const float var = fmaxf(sq * (1.0f / CIN) - mu * mu, 0.0f);
      const float rs = rsqrtf(var + 1e-5f);
      const float mk = mask[rbase + rr];       // rid == s*N + i indexes mask
      ushort4 p;
      p.x = f2bf(((v[rr].x - mu) * rs * g4.x + b4.x) * mk);
      p.y = f2bf(((v[rr].y - mu) * rs * g4.y + b4.y) * mk);
      p.z = f2bf(((v[rr].z - mu) * rs * g4.z + b4.z) * mk);
      p.w = f2bf(((v[rr].w - mu) * rs * g4.w + b4.w) * mk);
      *(ushort4*)(mn_g + (size_t)(rbase + rr) * CIN + l * 4) = p;
    }
  } else if (b < 2112) {
    const int r = b - 2048;  // 0..63
    const float* src = (r < 32) ? (Wa + r * CIN) : (Wb + (r - 32) * CIN);
    wab_bf[r * CIN + t] = f2bf(src[t]);
  } else if (b < 2240) {
    // wo2[((ot*32+kk)*64 + lane)*8 + e] = Wo[o=ot*16+(lane&15)][c*32+d],
    // k' = kk*32 + (lane>>4)*8 + e
    const int r = b - 2112;  // 0..127
    #pragma unroll
    for (int q = 0; q < 4; q++) {
      const int f = r * 1024 + q * 256 + t;
      const int e = f & 7, l = (f >> 3) & 63, kk = (f >> 9) & 31, ot = f >> 14;
      const int kp = kk * 32 + (l >> 4) * 8 + e;
      const int c = kp & 31, d = kp >> 5;
      const int o = ot * 16 + (l & 15);
      wo2[f] = f2bf(Wo[o * 1024 + c * 32 + d]);
    }
  } else {
    const int i = b - 2240;  // 0..255
    float acc = 0.f;
    #pragma unroll 8
    for (int s = 0; s < S_DIM; s++)
      acc += mask[s * N_DIM + i] * mask[s * N_DIM + t];
    acc = fmaxf(acc, 1.0f);
    rnm[i * N_DIM + t] = 1.0f / acc;
  }
}

// ---------------------------------------------------------------------------
// K_proj: mn_g (bf16) -> a_t/b_t via MFMA.  Block = (i, 32-s group).
// a_t[(i*32+c)][s], b_t likewise (8192 x 128 bf16 each).
// ---------------------------------------------------------------------------
__global__ __launch_bounds__(256) void proj_kernel(
    const unsigned short* __restrict__ mn_g,
    const unsigned short* __restrict__ wab_bf,
    unsigned short* __restrict__ a_t, unsigned short* __restrict__ b_t) {
  __shared__ __align__(16) unsigned short mn[32][264];  // +8 pad
  const int i = blockIdx.x;
  const int s0 = blockIdx.y * 32;
  const int t = threadIdx.x, w = t >> 6, l = t & 63;
  const int lq = l >> 4, lr = l & 15;

  // Stage 32 rows x 256 ch bf16 (coalesced 512B row loads)
  #pragma unroll
  for (int rr = 0; rr < 8; rr++) {
    const int r = w * 8 + rr;
    const size_t rid = (size_t)(s0 + r) * N_DIM + i;
    *(ushort4*)(&mn[r][l * 4]) = *(const ushort4*)(mn_g + rid * CIN + l * 4);
  }
  __syncthreads();

  // MFMA: M=32 s-rows, N=64 [Wa|Wb], K=256  (round-2-verified fragments)
  const int wm = w & 1;   // s-half
  const int n2 = w >> 1;  // 0 -> a, 1 -> b
  f32x4 acc0 = {0.f, 0.f, 0.f, 0.f}, acc1 = {0.f, 0.f, 0.f, 0.f};
  #pragma unroll
  for (int ks = 0; ks < 8; ks++) {
    const int k0 = ks * 32 + lq * 8;
    const bf16x8 af = *(const bf16x8*)(&mn[wm * 16 + lr][k0]);
    const unsigned short* wrow = wab_bf + (n2 * 32 + lr) * CIN + k0;
    const bf16x8 bf0 = *(const bf16x8*)(wrow);
    const bf16x8 bf1 = *(const bf16x8*)(wrow + 16 * CIN);
    acc0 = __builtin_amdgcn_mfma_f32_16x16x32_bf16(af, bf0, acc0, 0, 0, 0);
    acc1 = __builtin_amdgcn_mfma_f32_16x16x32_bf16(af, bf1, acc1, 0, 0, 0);
  }

  unsigned short* dst = (n2 == 0) ? a_t : b_t;
  const int scol = s0 + wm * 16 + lq * 4;
  ushort4 q0, q1;
  q0.x = f2bf(acc0[0]); q0.y = f2bf(acc0[1]); q0.z = f2bf(acc0[2]); q0.w = f2bf(acc0[3]);
  q1.x = f2bf(acc1[0]); q1.y = f2bf(acc1[1]); q1.z = f2bf(acc1[2]); q1.w = f2bf(acc1[3]);
  *(ushort4*)(dst + ((size_t)(i * CH + lr)) * S_DIM + scol) = q0;
  *(ushort4*)(dst + ((size_t)(i * CH + 16 + lr)) * S_DIM + scol) = q1;
}

// ---------------------------------------------------------------------------
// fused: z-GEMM + Wo contraction, 256x256 z-tile (64 pairs), 16 waves,
// 128 KB dynamic LDS, XCD-compact block swizzle (grid = 1024 linear).
// ---------------------------------------------------------------------------
__global__ __launch_bounds__(1024, 4) void fused_kernel(
    const unsigned short* __restrict__ a_t, const unsigned short* __restrict__ b_t,
    const unsigned short* __restrict__ wo2, const float* __restrict__ rnm,
    const float* __restrict__ bo, float* __restrict__ out) {
  extern __shared__ __align__(16) unsigned short smem[];
  unsigned short* sA = smem;            // 256 x 128 = 64 KB
  unsigned short* sB = smem + 32768;    // 256 x 128 = 64 KB
  unsigned short* sZ = smem;            // 64 pairs x 1024 = 128 KB overlay

  const int t = threadIdx.x, w = t >> 6, l = t & 63;
  const int lq = l >> 4, lr = l & 15;
  // XCD-compact swizzle: round-robin dispatch -> XCD (lin&7) gets a
  // 4-row by-patch (full a_t 2MB + b_t slice 256KB + wo2 256KB < 4MB L2)
  const int lin = blockIdx.x;
  const int li = lin >> 3;
  const int by = ((lin & 7) << 2) | (li >> 5);
  const int bx = li & 31;

  // Stage: 4096 granules/tile; swizzle g' = g ^ (r&15)
  const unsigned short* srcA = a_t + (size_t)bx * 32768;
  const unsigned short* srcB = b_t + (size_t)by * 32768;
  #pragma unroll
  for (int it = 0; it < 4; it++) {
    const int idx = it * 1024 + t;       // granule 0..4095
    const int r = idx >> 4, g = idx & 15;
    const int dst = r * 128 + ((g ^ (r & 15)) * 8);
    *(bf16x8*)(&sA[dst]) = *(const bf16x8*)(srcA + idx * 8);
    *(bf16x8*)(&sB[dst]) = *(const bf16x8*)(srcB + idx * 8);
  }
  __syncthreads();

  // GEMM1: K=128 = 4 MFMA k-steps. Wave (wy,wx) owns 64x64.
  const int wy = (w >> 2) * 64, wx = (w & 3) * 64;
  f32x4 acc[4][4];
  #pragma unroll
  for (int a = 0; a < 4; a++)
    #pragma unroll
    for (int c = 0; c < 4; c++) acc[a][c] = (f32x4){0.f, 0.f, 0.f, 0.f};

  #pragma unroll
  for (int ks = 0; ks < 4; ks++) {
    const int g0 = ks * 4 + lq;
    bf16x8 afr[4], bfr[4];
    #pragma unroll
    for (int a = 0; a < 4; a++) {
      const int ra = wy + a * 16 + lr;
      afr[a] = *(const bf16x8*)(&sA[ra * 128 + ((g0 ^ (ra & 15)) * 8)]);
      const int rb = wx + a * 16 + lr;
      bfr[a] = *(const bf16x8*)(&sB[rb * 128 + ((g0 ^ (rb & 15)) * 8)]);
    }
    #pragma unroll
    for (int a = 0; a < 4; a++)
      #pragma unroll
      for (int c = 0; c < 4; c++)
        acc[a][c] = __builtin_amdgcn_mfma_f32_16x16x32_bf16(afr[a], bfr[c], acc[a][c], 0, 0, 0);
  }
  __syncthreads();

  // Transpose: acc (C/D layout) -> sZ[pair][k'=d*32+c], b64 writes.
  #pragma unroll
  for (int a = 0; a < 4; a++) {
    #pragma unroll
    for (int c = 0; c < 4; c++) {
      const int zrb = wy + a * 16 + lq * 4;
      const int zc  = wx + c * 16 + lr;
      const int pair = (zrb >> 5) * 8 + (zc >> 5);
      const int off = (zc & 31) * 32 + (zrb & 31);
      const int g = off >> 3;
      const int gp = (g & ~7) | ((g ^ (g >> 3) ^ pair) & 7);
      ushort4 q;
      q.x = f2bf(acc[a][c][0]); q.y = f2bf(acc[a][c][1]);
      q.z = f2bf(acc[a][c][2]); q.w = f2bf(acc[a][c][3]);
      *(ushort4*)(&sZ[pair * 1024 + gp * 8 + (off & 7)]) = q;
    }
  }
  __syncthreads();

  // GEMM2: wave = (ot = w>>1, pair-half = w&1); 2 M-frags share Wo frags.
  const int ot = w >> 1, wm2 = w & 1;
  const int p0 = wm2 * 32 + lr, p1 = p0 + 16;
  const unsigned short* wbase = wo2 + (size_t)ot * 16384 + (size_t)l * 8;
  f32x4 oa[2][2];
  oa[0][0] = oa[0][1] = oa[1][0] = oa[1][1] = (f32x4){0.f, 0.f, 0.f, 0.f};
  #pragma unroll 4
  for (int kk = 0; kk < 32; kk++) {
    const int g = kk * 4 + lq;
    const int gp0 = (g & ~7) | ((g ^ (g >> 3) ^ p0) & 7);
    const int gp1 = (g & ~7) | ((g ^ (g >> 3) ^ p1) & 7);
    const bf16x8 wf = *(const bf16x8*)(wbase + kk * 512);
    const bf16x8 z0 = *(const bf16x8*)(&sZ[p0 * 1024 + gp0 * 8]);
    const bf16x8 z1 = *(const bf16x8*)(&sZ[p1 * 1024 + gp1 * 8]);
    oa[0][kk & 1] = __builtin_amdgcn_mfma_f32_16x16x32_bf16(z0, wf, oa[0][kk & 1], 0, 0, 0);
    oa[1][kk & 1] = __builtin_amdgcn_mfma_f32_16x16x32_bf16(z1, wf, oa[1][kk & 1], 0, 0, 0);
  }

  const int o = ot * 16 + lr;
  const float bov = bo[o];
  #pragma unroll
  for (int f = 0; f < 2; f++) {
    #pragma unroll
    for (int r = 0; r < 4; r++) {
      const int pair = wm2 * 32 + f * 16 + lq * 4 + r;
      const int ii = bx * 8 + (pair >> 3);
      const int jj = by * 8 + (pair & 7);
      const float sc = rnm[ii * N_DIM + jj];
      out[((size_t)(ii * N_DIM + jj)) * COUT + o] =
          (oa[f][0][r] + oa[f][1][r]) * sc + bov;
    }
  }
}

// ---------------------------------------------------------------------------
extern "C" void kernel_launch(void* const* d_in, const int* in_sizes, int n_in,
                              void* d_out, int out_size, void* d_ws, size_t ws_size,
                              hipStream_t stream) {
  const float* m     = (const float*)d_in[0];
  const float* mask  = (const float*)d_in[1];
  const float* gamma = (const float*)d_in[2];
  const float* beta  = (const float*)d_in[3];
  const float* Wa    = (const float*)d_in[4];
  const float* Wb    = (const float*)d_in[5];
  const float* Wo    = (const float*)d_in[6];
  const float* bo    = (const float*)d_in[7];
  float* out = (float*)d_out;

  char* ws = (char*)d_ws;
  float*          rnm    = (float*)(ws);                     // 256 KB
  unsigned short* wo2    = (unsigned short*)(ws + 262144);   // 256 KB
  unsigned short* wab_bf = (unsigned short*)(ws + 524288);   //  32 KB
  unsigned short* a_t    = (unsigned short*)(ws + 557056);   //   2 MB
  unsigned short* b_t    = (unsigned short*)(ws + 2654208);  //   2 MB
  unsigned short* mn_g   = (unsigned short*)(ws + 4751360);  // 16.8 MB
  // total ws use: ~21.5 MB

  hipFuncSetAttribute((const void*)fused_kernel,
                      hipFuncAttributeMaxDynamicSharedMemorySize, 131072);

  k0_ln_prep<<<2496, 256, 0, stream>>>(m, mask, gamma, beta, Wa, Wb, Wo,
                                       rnm, wab_bf, wo2, mn_g);
  proj_kernel<<<dim3(256, 4), 256, 0, stream>>>(mn_g, wab_bf, a_t, b_t);
  fused_kernel<<<1024, 1024, 131072, stream>>>(a_t, b_t, wo2, rnm, bo, out);
}